// Round 1
// baseline (708.697 us; speedup 1.0000x reference)
//
#include <hip/hip_runtime.h>

// out[N, BATCH] = A[N,N] @ x[N,BATCH] + B[N,S] @ x2[S,BATCH]
// x2[s(i,j), b] = x[i,b] * x[j,b]  for triu pairs (i<=j), s in np.triu_indices order:
//   s = 0 at (0,0); nested loop i=0..N-1, j=i..N-1.
//
// Round 0: correct fp32 baseline (no fp32 MFMA on CDNA4 -> vector ALU).
// Factorization per output (n,b): sum_i x_i * (sum_{j>=i} B[n,s]*x_j)
// makes every inner-loop op an FMA.

constexpr int N_     = 128;
constexpr int S_     = 8256;
constexpr int BATCH_ = 16384;
constexpr int TB     = 64;   // batch columns per block
constexpr int TN     = 32;   // output rows per block

// block = 256 threads; thread handles 2 rows x 4 consecutive cols.
// LDS 32KB -> 4 blocks/CU (128KB of 160KB), 16 waves/CU.
__global__ __launch_bounds__(256, 4) void quad_expand_gemm(
    const float* __restrict__ x,
    const float* __restrict__ A,
    const float* __restrict__ B,
    float* __restrict__ out)
{
    __shared__ float xs[N_][TB];   // 128 x 64 fp32 = 32 KB

    const int t  = threadIdx.x;
    const int b0 = blockIdx.x * TB;
    const int n0 = blockIdx.y * TN;

    // Stage x tile: 8192 elems, 256 threads -> 32 each, coalesced.
    #pragma unroll
    for (int it = 0; it < (N_ * TB) / 256; ++it) {
        const int idx = it * 256 + t;
        const int r = idx >> 6;          // idx / TB
        const int c = idx & (TB - 1);    // idx % TB
        xs[r][c] = x[r * BATCH_ + b0 + c];
    }
    __syncthreads();

    const int c4 = (t & 15) << 2;            // column offset within tile (x4)
    const int nr = n0 + ((t >> 4) << 1);     // first of 2 output rows

    const float* __restrict__ Brow0 = B + (size_t)nr * S_;
    const float* __restrict__ Brow1 = Brow0 + S_;
    const float* __restrict__ Arow0 = A + nr * N_;
    const float* __restrict__ Arow1 = Arow0 + N_;

    float acc0[4] = {0.f, 0.f, 0.f, 0.f};
    float acc1[4] = {0.f, 0.f, 0.f, 0.f};

    int s = 0;
    for (int i = 0; i < N_; ++i) {
        const float4 xi = *(const float4*)&xs[i][c4];
        float t0[4] = {0.f, 0.f, 0.f, 0.f};
        float t1[4] = {0.f, 0.f, 0.f, 0.f};
        #pragma unroll 4
        for (int j = i; j < N_; ++j, ++s) {
            const float4 xj  = *(const float4*)&xs[j][c4];  // ds_read_b128
            const float  bv0 = Brow0[s];                    // uniform per 16 lanes
            const float  bv1 = Brow1[s];
            t0[0] += bv0 * xj.x;  t0[1] += bv0 * xj.y;
            t0[2] += bv0 * xj.z;  t0[3] += bv0 * xj.w;
            t1[0] += bv1 * xj.x;  t1[1] += bv1 * xj.y;
            t1[2] += bv1 * xj.z;  t1[3] += bv1 * xj.w;
        }
        acc0[0] += xi.x * t0[0];  acc0[1] += xi.y * t0[1];
        acc0[2] += xi.z * t0[2];  acc0[3] += xi.w * t0[3];
        acc1[0] += xi.x * t1[0];  acc1[1] += xi.y * t1[1];
        acc1[2] += xi.z * t1[2];  acc1[3] += xi.w * t1[3];
    }

    // A @ x part
    #pragma unroll 4
    for (int k = 0; k < N_; ++k) {
        const float4 xk = *(const float4*)&xs[k][c4];
        const float  a0 = Arow0[k];
        const float  a1 = Arow1[k];
        acc0[0] += a0 * xk.x;  acc0[1] += a0 * xk.y;
        acc0[2] += a0 * xk.z;  acc0[3] += a0 * xk.w;
        acc1[0] += a1 * xk.x;  acc1[1] += a1 * xk.y;
        acc1[2] += a1 * xk.z;  acc1[3] += a1 * xk.w;
    }

    float4* o0 = (float4*)&out[(size_t)nr * BATCH_ + b0 + c4];
    float4* o1 = (float4*)&out[(size_t)(nr + 1) * BATCH_ + b0 + c4];
    *o0 = make_float4(acc0[0], acc0[1], acc0[2], acc0[3]);
    *o1 = make_float4(acc1[0], acc1[1], acc1[2], acc1[3]);
}

extern "C" void kernel_launch(void* const* d_in, const int* in_sizes, int n_in,
                              void* d_out, int out_size, void* d_ws, size_t ws_size,
                              hipStream_t stream) {
    const float* x = (const float*)d_in[0];   // [128, 16384]
    const float* A = (const float*)d_in[1];   // [128, 128]
    const float* B = (const float*)d_in[2];   // [128, 8256]
    float* out = (float*)d_out;               // [128, 16384]

    dim3 grid(BATCH_ / TB, N_ / TN);          // (256, 4) = 1024 blocks
    dim3 block(256);
    quad_expand_gemm<<<grid, block, 0, stream>>>(x, A, B, out);
}

// Round 2
// 241.965 us; speedup vs baseline: 2.9289x; 2.9289x over previous
//
#include <hip/hip_runtime.h>

// out[128,16384] = A[128,128] @ x[128,16384] + B[128,8256] @ x2[8256,16384]
// x2[s(i,j),b] = x[i,b]*x[j,b], triu order (i<=j).
//
// Treated as ONE bf16 MFMA GEMM: W = [A|B] (128 x 8384), X2s = [x; x2] (8384 x 16384).
// Phase 1a: pairs[s] = (i, j) table.
// Phase 1b: W -> bf16, K-tiled + XOR-swizzled layout matching the LDS image
//           so phase 2 can stage via global_load_lds (16B, contiguous-lane).
// Phase 2:  grid 256 blocks (batch tiles of 64), 4 waves, tile 128x64, BK=64,
//           mfma_f32_16x16x32_bf16, wave tile 64x32 (4x2 frags).
//           x2 tile generated per K-step from an LDS-resident x-tile (xt).

constexpr int N_     = 128;
constexpr int S_     = 8256;
constexpr int BATCH_ = 16384;
constexpr int KTOT   = 8384;        // 128 + 8256 = 131*64
constexpr int NKT    = 131;
constexpr int XT_LD  = 131;         // xt row stride (odd -> 2-way bank pattern)
constexpr int X2_LD  = 88;          // x2l row stride (16B-aligned rows, 2-way banks)
constexpr size_t WT_BYTES  = (size_t)NKT * 128 * 64 * 2;  // 2,146,304
constexpr size_t PAIRS_OFF = WT_BYTES;                    // 16B aligned

typedef __attribute__((ext_vector_type(8))) short short8;
typedef __attribute__((ext_vector_type(4))) float f32x4;

__device__ __forceinline__ float bf2f(ushort h) {
    unsigned u = (unsigned)h << 16;
    float f;
    __builtin_memcpy(&f, &u, 4);
    return f;
}
__device__ __forceinline__ ushort f2bf(float f) {
    unsigned u;
    __builtin_memcpy(&u, &f, 4);
    u = (u + 0x7FFFu + ((u >> 16) & 1u)) >> 16;   // round-to-nearest-even
    return (ushort)u;
}

// ---------------- phase 1a: triu pair table ----------------
__global__ void build_pairs(ushort* __restrict__ pairs) {
    int s = blockIdx.x * 256 + threadIdx.x;
    if (s >= S_) return;
    double d = 257.0 * 257.0 - 8.0 * (double)s;
    int i = (int)((257.0 - sqrt(d)) * 0.5);
    if (i < 0) i = 0;
    if (i > 127) i = 127;
    while (i < 127 && (i + 1) * (257 - (i + 1)) / 2 <= s) ++i;
    while (i > 0 && i * (257 - i) / 2 > s) --i;
    int j = i + (s - i * (257 - i) / 2);
    pairs[s] = (ushort)(i | (j << 8));
}

// ---------------- phase 1b: W -> bf16, tiled+swizzled ----------------
// Element e = kt*8192 + m*64 + sg*8 + r holds W[m][kt*64 + kl],
// kl = ((sg ^ (m&7))<<3) | r  (16B-granule XOR swizzle per row).
__global__ void build_wt(const float* __restrict__ A, const float* __restrict__ B,
                         ushort* __restrict__ wt) {
    int e  = blockIdx.x * 256 + threadIdx.x;   // exactly 131*8192 = 4192*256
    int kt = e >> 13;
    int p  = e & 8191;
    int m  = p >> 6;
    int q  = p & 63;
    int sg = q >> 3, r = q & 7;
    int kl = ((sg ^ (m & 7)) << 3) | r;
    int k  = kt * 64 + kl;
    float v = (k < 128) ? A[m * 128 + k] : B[(size_t)m * S_ + (k - 128)];
    wt[e] = f2bf(v);
}

// ---------------- phase 2: fused MFMA GEMM ----------------
__global__ __launch_bounds__(256) void gemm_mfma(
    const float*  __restrict__ x,
    const ushort* __restrict__ wt,
    const ushort* __restrict__ pairs,
    float* __restrict__ out)
{
    __shared__ ushort wl[128 * 64];        // 16 KB, swizzled W tile (LDS image of wt tile)
    __shared__ ushort xt[64 * XT_LD];      // 16.4 KB, xt[n][r] = bf16(x[r][b0+n])
    __shared__ ushort x2l[64 * X2_LD];     // 11 KB, x2l[n][k] (X2^T tile, k-contiguous)

    const int t    = threadIdx.x;
    const int b0   = blockIdx.x * 64;
    const int lane = t & 63;
    const int w    = t >> 6;
    const int wm   = w >> 1, wn = w & 1;
    const int l16  = lane & 15, quad = lane >> 4;
    const int n    = t & 63;               // gen: column owned by this thread
    const int krb  = w;                    // gen: k-octet base (wave index)

    // ---- stage xt (once; K-invariant) ----
    #pragma unroll
    for (int ps = 0; ps < 32; ++ps) {
        int idx = ps * 256 + t;
        int rr = idx >> 6, nn = idx & 63;
        xt[nn * XT_LD + rr] = f2bf(x[(size_t)rr * BATCH_ + b0 + nn]);
    }
    __syncthreads();

    f32x4 acc[4][2];
    #pragma unroll
    for (int mt = 0; mt < 4; ++mt)
        #pragma unroll
        for (int nt = 0; nt < 2; ++nt)
            acc[mt][nt] = (f32x4){0.f, 0.f, 0.f, 0.f};

    for (int kt = 0; kt < NKT; ++kt) {
        // ---- async W stage: wave w covers bytes [w*4K, w*4K+4K) of the 16KB tile
        const ushort* gsrc = wt + (size_t)kt * 8192;
        #pragma unroll
        for (int q2 = 0; q2 < 4; ++q2) {
            int off_e = w * 2048 + q2 * 512 + lane * 8;   // elems (16B/lane)
            __builtin_amdgcn_global_load_lds(
                (const __attribute__((address_space(1))) void*)(gsrc + off_e),
                (__attribute__((address_space(3))) void*)(wl + w * 2048 + q2 * 512),
                16, 0, 0);
        }

        // ---- generate x2 tile (reads xt, writes x2l) ----
        const int kbase = kt * 64;
        if (kbase >= 128) {
            const int sb = kbase - 128;
            #pragma unroll
            for (int p = 0; p < 2; ++p) {
                const int kr = krb + p * 4;
                const int s0 = sb + kr * 8;
                const uint4 pk = *(const uint4*)(pairs + s0);   // 8 (i,j) pairs, 16B
                const uint pr[4] = {pk.x, pk.y, pk.z, pk.w};
                const ushort* xrow = &xt[n * XT_LD];
                float prods[8];
                const uint i0 = pr[0] & 0xFFu;
                const uint i7 = (pr[3] >> 16) & 0xFFu;
                if (i0 == i7) {                      // wave-uniform fast path: const i
                    const float xi = bf2f(xrow[i0]);
                    #pragma unroll
                    for (int e = 0; e < 8; ++e) {
                        uint ent = (pr[e >> 1] >> ((e & 1) * 16)) & 0xFFFFu;
                        prods[e] = xi * bf2f(xrow[ent >> 8]);
                    }
                } else {
                    #pragma unroll
                    for (int e = 0; e < 8; ++e) {
                        uint ent = (pr[e >> 1] >> ((e & 1) * 16)) & 0xFFFFu;
                        prods[e] = bf2f(xrow[ent & 0xFFu]) * bf2f(xrow[ent >> 8]);
                    }
                }
                uint4 wv;
                wv.x = (uint)f2bf(prods[0]) | ((uint)f2bf(prods[1]) << 16);
                wv.y = (uint)f2bf(prods[2]) | ((uint)f2bf(prods[3]) << 16);
                wv.z = (uint)f2bf(prods[4]) | ((uint)f2bf(prods[5]) << 16);
                wv.w = (uint)f2bf(prods[6]) | ((uint)f2bf(prods[7]) << 16);
                *(uint4*)&x2l[n * X2_LD + kr * 8] = wv;         // ds_write_b128
            }
        } else {
            // k < 128: X2s rows are x itself — copy from xt
            #pragma unroll
            for (int p = 0; p < 2; ++p) {
                const int kr = krb + p * 4;
                const ushort* src = &xt[n * XT_LD + kbase + kr * 8];
                uint4 wv;
                wv.x = (uint)src[0] | ((uint)src[1] << 16);
                wv.y = (uint)src[2] | ((uint)src[3] << 16);
                wv.z = (uint)src[4] | ((uint)src[5] << 16);
                wv.w = (uint)src[6] | ((uint)src[7] << 16);
                *(uint4*)&x2l[n * X2_LD + kr * 8] = wv;
            }
        }
        __syncthreads();   // drains global_load_lds (vmcnt0) + gen writes

        // ---- MFMA over BK=64 (2 x K32) ----
        #pragma unroll
        for (int kk = 0; kk < 2; ++kk) {
            const int koff = kk * 32 + quad * 8;
            short8 af[4], bf_[2];
            #pragma unroll
            for (int mt = 0; mt < 4; ++mt) {
                const int m  = wm * 64 + mt * 16 + l16;
                const int sg = (koff >> 3) ^ (m & 7);
                af[mt] = *(const short8*)&wl[m * 64 + sg * 8];
            }
            #pragma unroll
            for (int nt = 0; nt < 2; ++nt) {
                const int nn = wn * 32 + nt * 16 + l16;
                bf_[nt] = *(const short8*)&x2l[nn * X2_LD + koff];
            }
            #pragma unroll
            for (int mt = 0; mt < 4; ++mt)
                #pragma unroll
                for (int nt = 0; nt < 2; ++nt)
                    acc[mt][nt] = __builtin_amdgcn_mfma_f32_16x16x32_bf16(
                        af[mt], bf_[nt], acc[mt][nt], 0, 0, 0);
        }
        __syncthreads();   // protect wl/x2l before next stage
    }

    // ---- epilogue: C/D layout col=lane&15, row=quad*4+reg ----
    #pragma unroll
    for (int mt = 0; mt < 4; ++mt) {
        #pragma unroll
        for (int nt = 0; nt < 2; ++nt) {
            const int mbase = wm * 64 + mt * 16 + quad * 4;
            const size_t col = (size_t)b0 + wn * 32 + nt * 16 + l16;
            #pragma unroll
            for (int r = 0; r < 4; ++r)
                out[(size_t)(mbase + r) * BATCH_ + col] = acc[mt][nt][r];
        }
    }
}

extern "C" void kernel_launch(void* const* d_in, const int* in_sizes, int n_in,
                              void* d_out, int out_size, void* d_ws, size_t ws_size,
                              hipStream_t stream) {
    const float* x = (const float*)d_in[0];   // [128, 16384]
    const float* A = (const float*)d_in[1];   // [128, 128]
    const float* B = (const float*)d_in[2];   // [128, 8256]
    float* out = (float*)d_out;               // [128, 16384]

    ushort* wt    = (ushort*)d_ws;                          // 2.05 MB
    ushort* pairs = (ushort*)((char*)d_ws + PAIRS_OFF);     // 16.5 KB

    build_pairs<<<(S_ + 255) / 256, 256, 0, stream>>>(pairs);
    build_wt<<<4192, 256, 0, stream>>>(A, B, wt);
    gemm_mfma<<<256, 256, 0, stream>>>(x, wt, pairs, out);
}